// Round 1
// 575.786 us; speedup vs baseline: 1.0263x; 1.0263x over previous
//
#include <hip/hip_runtime.h>

// 100 / ln(2): reference divides by T=0.01 then uses e-base LSE; we work in
// base-2 throughout (v_exp_f32 computes 2^x natively).
#define SCALE 144.269504088896340736f

// DPP move helper (compile-time ctrl). bound_ctrl=true, all rows/banks.
template <int CTRL>
__device__ __forceinline__ float dppf(float x) {
    return __builtin_bit_cast(
        float, __builtin_amdgcn_update_dpp(0, __builtin_bit_cast(int, x),
                                           CTRL, 0xF, 0xF, true));
}

// Reduce over the 4 "b" lanes (quad): quad_perm ror1 (0x39), ror2 (0x4E).
__device__ __forceinline__ float qsum(float x) {
    x += dppf<0x39>(x);
    x += dppf<0x4E>(x);
    return x;  // all 4 lanes hold the total
}
__device__ __forceinline__ float qmax(float x) {
    x = fmaxf(x, dppf<0x39>(x));
    x = fmaxf(x, dppf<0x4E>(x));
    return x;
}
// Reduce over the 4 "a" lanes (stride 4 inside a 16-lane DPP row):
// row_ror:4 (0x124), row_ror:8 (0x128). (l+4k) mod 16 preserves b = l%4.
__device__ __forceinline__ float asum(float x) {
    x += dppf<0x124>(x);
    x += dppf<0x128>(x);
    return x;
}
__device__ __forceinline__ float amax(float x) {
    x = fmaxf(x, dppf<0x124>(x));
    x = fmaxf(x, dppf<0x128>(x));
    return x;
}

typedef float f32x4 __attribute__((ext_vector_type(4)));

// Unaligned-tolerant 16B load/store (row chunks are only 4B-aligned: b*36B).
// gfx9+ supports unaligned global wide access; worst case the backend splits.
__device__ __forceinline__ f32x4 load4u(const float* p) {
    f32x4 v;
    __builtin_memcpy(&v, p, 16);
    return v;
}
__device__ __forceinline__ void store4u(float* p, f32x4 v) {
    __builtin_memcpy(p, &v, 16);
}

// One matrix per 16-lane DPP row; 4 matrices per wave; 16 per 256-thread block.
// Lane (q,a,b): holds C[a*9+r][b*9+s], r,s in [0,9): 81 VGPRs.
// launch_bounds min-waves = 3 (not 4): measured steady-state occupancy is
// 3 blocks/CU anyway; the 128-reg cap from (256,4) only forced the allocator
// to shunt C[] into AGPRs (rocprof showed VGPR_Count=64 for a ~110-float live
// set) and pay v_accvgpr shuttle ops in the hot loop.
__global__ __launch_bounds__(256, 3) void sinkhorn_kernel(
    const float* __restrict__ in, float* __restrict__ out) {
    const int lane = threadIdx.x & 63;
    const int wv   = threadIdx.x >> 6;
    const int q    = lane >> 4;         // matrix within wave
    const int a    = (lane >> 2) & 3;   // row-block
    const int b    = lane & 3;          // col-block
    const int m    = blockIdx.x * 16 + wv * 4 + q;

    const float* src = in  + (size_t)m * 1296 + (a * 9) * 36 + b * 9;
    float*       dst = out + (size_t)m * 1296 + (a * 9) * 36 + b * 9;

    // Load RAW values (scale is folded into the exp2 args via FMA below;
    // max() commutes exactly with multiplication by a positive constant).
    float C[81];
    #pragma unroll
    for (int r = 0; r < 9; ++r) {
        f32x4 v0 = load4u(src + r * 36);
        f32x4 v1 = load4u(src + r * 36 + 4);
        #pragma unroll
        for (int s = 0; s < 4; ++s) C[r * 9 + s] = v0[s];
        #pragma unroll
        for (int s = 0; s < 4; ++s) C[r * 9 + 4 + s] = v1[s];
        C[r * 9 + 8] = src[r * 36 + 8];
    }

    // a2s[r] = SCALE * (row max of raw)  (local max over s, then over b-lanes)
    float a2s[9], u[9], w[9];
    #pragma unroll
    for (int r = 0; r < 9; ++r) {
        float mx = C[r * 9];
        #pragma unroll
        for (int s = 1; s < 9; ++s) mx = fmaxf(mx, C[r * 9 + s]);
        a2s[r] = qmax(mx) * SCALE;
    }

    // u^(1)_i = 1 / sum_j 2^(L - a)   (first row step; avoids degenerate w0)
    #pragma unroll
    for (int r = 0; r < 9; ++r) {
        float acc = 0.f;
        #pragma unroll
        for (int s = 0; s < 9; ++s)
            acc += __builtin_amdgcn_exp2f(
                __builtin_fmaf(C[r * 9 + s], SCALE, -a2s[r]));
        u[r] = __builtin_amdgcn_rcpf(qsum(acc));
    }

    // b2s[s] = col max of (L - a2), already in scaled units
    // (local over r, then over a-lanes)
    float b2s[9];
    #pragma unroll
    for (int s = 0; s < 9; ++s) {
        float mx = __builtin_fmaf(C[s], SCALE, -a2s[0]);
        #pragma unroll
        for (int r = 1; r < 9; ++r)
            mx = fmaxf(mx, __builtin_fmaf(C[r * 9 + s], SCALE, -a2s[r]));
        b2s[s] = amax(mx);
    }

    // C = 2^(L - a2 - b2): every row AND every column contains a ~1.0.
    // NOTE: must stay in log domain through both subtracts — a linear-domain
    // shortcut (exp2 once, rescale by 1/colmax) underflows whole columns to 0
    // for ~27% of matrices (range here is up to ~600 in log2).
    #pragma unroll
    for (int r = 0; r < 9; ++r)
        #pragma unroll
        for (int s = 0; s < 9; ++s)
            C[r * 9 + s] = __builtin_amdgcn_exp2f(
                __builtin_fmaf(C[r * 9 + s], SCALE, -a2s[r]) - b2s[s]);

    // w^(1)_j = 1 / sum_i C_ij u_i   (first col step)
    #pragma unroll
    for (int s = 0; s < 9; ++s) {
        float acc = 0.f;
        #pragma unroll
        for (int r = 0; r < 9; ++r) acc = fmaf(C[r * 9 + s], u[r], acc);
        w[s] = __builtin_amdgcn_rcpf(asum(acc));
    }

    // 20 more full iterations (21 row steps + 21 col steps total)
    #pragma unroll 1
    for (int it = 0; it < 20; ++it) {
        #pragma unroll
        for (int r = 0; r < 9; ++r) {
            float acc = 0.f;
            #pragma unroll
            for (int s = 0; s < 9; ++s) acc = fmaf(C[r * 9 + s], w[s], acc);
            u[r] = __builtin_amdgcn_rcpf(qsum(acc));
        }
        #pragma unroll
        for (int s = 0; s < 9; ++s) {
            float acc = 0.f;
            #pragma unroll
            for (int r = 0; r < 9; ++r) acc = fmaf(C[r * 9 + s], u[r], acc);
            w[s] = __builtin_amdgcn_rcpf(asum(acc));
        }
    }

    // P = C * u_i * w_j
    #pragma unroll
    for (int r = 0; r < 9; ++r) {
        const float ur = u[r];
        float p[9];
        #pragma unroll
        for (int s = 0; s < 9; ++s) p[s] = C[r * 9 + s] * ur * w[s];
        f32x4 v0, v1;
        #pragma unroll
        for (int s = 0; s < 4; ++s) v0[s] = p[s];
        #pragma unroll
        for (int s = 0; s < 4; ++s) v1[s] = p[4 + s];
        store4u(dst + r * 36, v0);
        store4u(dst + r * 36 + 4, v1);
        dst[r * 36 + 8] = p[8];
    }
}

extern "C" void kernel_launch(void* const* d_in, const int* in_sizes, int n_in,
                              void* d_out, int out_size, void* d_ws, size_t ws_size,
                              hipStream_t stream) {
    const float* in  = (const float*)d_in[0];
    float*       out = (float*)d_out;
    // 65536 matrices, 16 per block -> 4096 blocks of 256 threads.
    sinkhorn_kernel<<<dim3(4096), dim3(256), 0, stream>>>(in, out);
}

// Round 2
// 571.840 us; speedup vs baseline: 1.0334x; 1.0069x over previous
//
#include <hip/hip_runtime.h>

// 100 / ln(2): reference divides by T=0.01 then uses e-base LSE; we work in
// base-2 throughout (v_exp_f32 computes 2^x natively).
#define SCALE 144.269504088896340736f

typedef float f32x2 __attribute__((ext_vector_type(2)));
typedef float f32x4 __attribute__((ext_vector_type(4)));

// DPP move helper (compile-time ctrl). bound_ctrl=true, all rows/banks.
template <int CTRL>
__device__ __forceinline__ float dppf(float x) {
    return __builtin_bit_cast(
        float, __builtin_amdgcn_update_dpp(0, __builtin_bit_cast(int, x),
                                           CTRL, 0xF, 0xF, true));
}

// Reduce over the 4 "b" lanes (quad): quad_perm rot1 (0x39), rot2 (0x4E).
__device__ __forceinline__ float qsum(float x) {
    x += dppf<0x39>(x);
    x += dppf<0x4E>(x);
    return x;  // all 4 lanes hold the total
}
__device__ __forceinline__ float qmax(float x) {
    x = fmaxf(x, dppf<0x39>(x));
    x = fmaxf(x, dppf<0x4E>(x));
    return x;
}
// Reduce over the 4 "a" lanes (stride 4 inside a 16-lane DPP row):
// row_ror:4 (0x124), row_ror:8 (0x128). (l+4k) mod 16 preserves b = l%4.
__device__ __forceinline__ float asum(float x) {
    x += dppf<0x124>(x);
    x += dppf<0x128>(x);
    return x;
}
__device__ __forceinline__ float amax(float x) {
    x = fmaxf(x, dppf<0x124>(x));
    x = fmaxf(x, dppf<0x128>(x));
    return x;
}

// Unaligned-tolerant 16B load/store (row chunks are only 4B-aligned: b*36B).
__device__ __forceinline__ f32x4 load4u(const float* p) {
    f32x4 v;
    __builtin_memcpy(&v, p, 16);
    return v;
}
__device__ __forceinline__ void store4u(float* p, f32x4 v) {
    __builtin_memcpy(p, &v, 16);
}

// One matrix per 16-lane DPP row; 4 matrices per wave; 16 per 256-thread block.
// Lane (q,a,b): holds C[a*9+r][b*9+s], r,s in [0,9).
// C stored as f32x2 pairs along s (C2[r][p] = cols 2p,2p+1) + odd col C8[r]:
// gfx950 has v_pk_fma_f32 (VOP3P), so pairs halve the fma instruction count:
//  - row step: horizontal pairs (4 pk_fma + 1 fma per row)
//  - col step: broadcast (u,u) multiplier -> two column sums per pk_fma
// Precision identical to scalar (pk_fma is full IEEE f32 per lane).
__global__ __launch_bounds__(256, 3) void sinkhorn_kernel(
    const float* __restrict__ in, float* __restrict__ out) {
    const int lane = threadIdx.x & 63;
    const int wv   = threadIdx.x >> 6;
    const int q    = lane >> 4;         // matrix within wave
    const int a    = (lane >> 2) & 3;   // row-block
    const int b    = lane & 3;          // col-block
    const int m    = blockIdx.x * 16 + wv * 4 + q;

    const float* src = in  + (size_t)m * 1296 + (a * 9) * 36 + b * 9;
    float*       dst = out + (size_t)m * 1296 + (a * 9) * 36 + b * 9;

    f32x2 C2[9][4];
    float C8[9];
    #pragma unroll
    for (int r = 0; r < 9; ++r) {
        f32x4 v0 = load4u(src + r * 36);
        f32x4 v1 = load4u(src + r * 36 + 4);
        C2[r][0] = f32x2{v0.x, v0.y};
        C2[r][1] = f32x2{v0.z, v0.w};
        C2[r][2] = f32x2{v1.x, v1.y};
        C2[r][3] = f32x2{v1.z, v1.w};
        C8[r] = src[r * 36 + 8];
    }

    // a2s[r] = SCALE * (row max of raw); max commutes with positive scaling.
    float a2s[9];
    #pragma unroll
    for (int r = 0; r < 9; ++r) {
        float mx = C8[r];
        #pragma unroll
        for (int p = 0; p < 4; ++p)
            mx = fmaxf(mx, fmaxf(C2[r][p].x, C2[r][p].y));
        a2s[r] = qmax(mx) * SCALE;
    }

    // In place: X = L*SCALE - a2  (pk_fma pairs; 41 ops instead of 81)
    const f32x2 S2 = {SCALE, SCALE};
    #pragma unroll
    for (int r = 0; r < 9; ++r) {
        const f32x2 a2p = {a2s[r], a2s[r]};
        #pragma unroll
        for (int p = 0; p < 4; ++p) C2[r][p] = C2[r][p] * S2 - a2p;
        C8[r] = __builtin_fmaf(C8[r], SCALE, -a2s[r]);
    }

    // b2[s] = col max of X (per column-pair; cross-lane over a-lanes)
    f32x2 b22[4];
    float b28;
    #pragma unroll
    for (int p = 0; p < 4; ++p) {
        f32x2 mx = C2[0][p];
        #pragma unroll
        for (int r = 1; r < 9; ++r) {
            mx.x = fmaxf(mx.x, C2[r][p].x);
            mx.y = fmaxf(mx.y, C2[r][p].y);
        }
        b22[p] = f32x2{amax(mx.x), amax(mx.y)};
    }
    {
        float mx = C8[0];
        #pragma unroll
        for (int r = 1; r < 9; ++r) mx = fmaxf(mx, C8[r]);
        b28 = amax(mx);
    }

    // C = 2^(X - b2): every column contains an exact 1.0.
    // NOTE: must stay in log domain through both subtracts — a linear-domain
    // shortcut underflows whole columns to 0 (range up to ~±1300 in log2).
    #pragma unroll
    for (int r = 0; r < 9; ++r) {
        #pragma unroll
        for (int p = 0; p < 4; ++p) {
            const f32x2 e = C2[r][p] - b22[p];  // v_pk_add (neg)
            C2[r][p].x = __builtin_amdgcn_exp2f(e.x);
            C2[r][p].y = __builtin_amdgcn_exp2f(e.y);
        }
        C8[r] = __builtin_amdgcn_exp2f(C8[r] - b28);
    }

    // First row step: u1_r = 1/Σ_s 2^{X} = 1/Σ_s C·2^{b2}  (reuses rebuilt C;
    // saves the second 81-wide exp2 pass. Underflow agrees: 2^{b2}->0 only
    // where the whole column is already ~0.)
    f32x2 u2[9];  // broadcast pairs (u,u)
    {
        f32x2 t2[4];
        #pragma unroll
        for (int p = 0; p < 4; ++p)
            t2[p] = f32x2{__builtin_amdgcn_exp2f(b22[p].x),
                          __builtin_amdgcn_exp2f(b22[p].y)};
        const float t8 = __builtin_amdgcn_exp2f(b28);
        #pragma unroll
        for (int r = 0; r < 9; ++r) {
            f32x2 acc2 = C2[r][0] * t2[0];
            #pragma unroll
            for (int p = 1; p < 4; ++p) acc2 += C2[r][p] * t2[p];
            const float acc = __builtin_fmaf(C8[r], t8, acc2.x) + acc2.y;
            const float ur = __builtin_amdgcn_rcpf(qsum(acc));
            u2[r] = f32x2{ur, ur};
        }
    }

    f32x2 w2[4];
    float w8;

    // Col step: w_s = 1/Σ_r C_rs u_r. Broadcast (u,u) pairs -> 2 cols/pk_fma.
    auto col_step = [&]() {
        f32x2 acc[4];
        #pragma unroll
        for (int p = 0; p < 4; ++p) acc[p] = C2[0][p] * u2[0];
        float acc8 = C8[0] * u2[0].x;
        #pragma unroll
        for (int r = 1; r < 9; ++r) {
            #pragma unroll
            for (int p = 0; p < 4; ++p) acc[p] += C2[r][p] * u2[r];
            acc8 = __builtin_fmaf(C8[r], u2[r].x, acc8);
        }
        #pragma unroll
        for (int p = 0; p < 4; ++p)
            w2[p] = f32x2{__builtin_amdgcn_rcpf(asum(acc[p].x)),
                          __builtin_amdgcn_rcpf(asum(acc[p].y))};
        w8 = __builtin_amdgcn_rcpf(asum(acc8));
    };

    // Row step: u_r = 1/Σ_s C_rs w_s. Horizontal pairs.
    auto row_step = [&]() {
        #pragma unroll
        for (int r = 0; r < 9; ++r) {
            f32x2 acc2 = C2[r][0] * w2[0];
            #pragma unroll
            for (int p = 1; p < 4; ++p) acc2 += C2[r][p] * w2[p];
            const float acc = __builtin_fmaf(C8[r], w8, acc2.x) + acc2.y;
            const float ur = __builtin_amdgcn_rcpf(qsum(acc));
            u2[r] = f32x2{ur, ur};
        }
    };

    col_step();  // first col step

    // 20 more full iterations (21 row steps + 21 col steps total)
    #pragma unroll 1
    for (int it = 0; it < 20; ++it) {
        row_step();
        col_step();
    }

    // P = C * u_r * w_s
    #pragma unroll
    for (int r = 0; r < 9; ++r) {
        const f32x2 uu = u2[r];
        const f32x2 t0 = C2[r][0] * uu * w2[0];
        const f32x2 t1 = C2[r][1] * uu * w2[1];
        const f32x2 t2_ = C2[r][2] * uu * w2[2];
        const f32x2 t3 = C2[r][3] * uu * w2[3];
        store4u(dst + r * 36, f32x4{t0.x, t0.y, t1.x, t1.y});
        store4u(dst + r * 36 + 4, f32x4{t2_.x, t2_.y, t3.x, t3.y});
        dst[r * 36 + 8] = C8[r] * uu.x * w8;
    }
}

extern "C" void kernel_launch(void* const* d_in, const int* in_sizes, int n_in,
                              void* d_out, int out_size, void* d_ws, size_t ws_size,
                              hipStream_t stream) {
    const float* in  = (const float*)d_in[0];
    float*       out = (float*)d_out;
    // 65536 matrices, 16 per block -> 4096 blocks of 256 threads.
    sinkhorn_kernel<<<dim3(4096), dim3(256), 0, stream>>>(in, out);
}